// Round 11
// baseline (272.696 us; speedup 1.0000x reference)
//
#include <hip/hip_runtime.h>
#include <hip/hip_bf16.h>
#include <math.h>

// R21: XCD-chunked block swizzle (T1) on all three GEMMs; core code is
// byte-identical to R17 (best=257.4: qkv sb64 83us stable, scores db64,
// pv db64+m-interleave, single-S softmax). R20 post-mortem: scores ~70us
// under {db64@depth2.1, db32@4.25, sb64@4.25} -> depth/schedule knobs
// refuted; suspect = panel staging streams from L3 because panel-sharing
// blocks round-robin across XCDs (no L2 retention). Fix: bijective chunked
// swizzle (m204; all grids %8==0) so consecutive lids (which share B-panels)
// land on one XCD: qkv 192/XCD (weight panel), scores 68/XCD over the 544
// ACTIVE triangular tiles (dead blocks eliminated; row-major t shares
// Q-panel), pv 64/XCD (= 4 complete V-panels). Latency-bound-at-depth-2 is
// T1's untested regime - this round is the test. Pre-commit: >=258 ->
// T1-null here, scores/pv shape-pinned.
// Swizzle-in-LDS (R17-verified, conflicts=0): row holds 8 chunks, phys p at
// row r = logical p^(r&7); staging pre-swizzles GLOBAL chunk ((l&7)^(l>>3)),
// LDS dest linear (m104/m173); read phys = (quad^(kk<<2))^(l16&7).

typedef __bf16 bf16x8 __attribute__((ext_vector_type(8)));
typedef float  f32x4  __attribute__((ext_vector_type(4)));

__device__ __forceinline__ ushort f2bf(float f) {
    __hip_bfloat16 h = __float2bfloat16(f);
    return *reinterpret_cast<ushort*>(&h);
}

__device__ __forceinline__ void async_load16(const ushort* g, ushort* l) {
    __builtin_amdgcn_global_load_lds(
        (const __attribute__((address_space(1))) void*)g,
        (__attribute__((address_space(3))) void*)l, 16, 0, 0);
}

// One launch for all 4 fp32->bf16 conversions + RoPE cos/sin table.
// grid (8192, 5): y<4 = conversions, y==4 = table gen (first 4096 x-blocks).
__global__ __launch_bounds__(256) void cvt_all_kernel(
    const float* __restrict__ x,  const float* __restrict__ wq,
    const float* __restrict__ wk, const float* __restrict__ wv,
    ushort* __restrict__ xb, ushort* __restrict__ wqb,
    ushort* __restrict__ wkb, ushort* __restrict__ wvb,
    float2* __restrict__ cs)
{
    const int t = blockIdx.y;
    if (t == 4) {
        // cs[pos*512 + i] = (cos(pos*phi_i), sin(pos*phi_i)),
        // phi_i = 10000^(-2*(i-1)/1024)  (reference's -1 quirk preserved).
        const int idx = blockIdx.x * 256 + threadIdx.x;
        if (idx < 2048 * 512) {
            const int pos = idx >> 9, i = idx & 511;
            const float phi = powf(10000.0f, -2.0f * ((float)i - 1.0f) / 1024.0f);
            float s, c;
            sincosf((float)pos * phi, &s, &c);
            cs[idx] = make_float2(c, s);
        }
        return;
    }
    const float* in  = (t == 0) ? x  : (t == 1) ? wq  : (t == 2) ? wk  : wv;
    ushort*      out = (t == 0) ? xb : (t == 1) ? wqb : (t == 2) ? wkb : wvb;
    const int n4 = (t == 0) ? 2097152 : 262144;
    int i = blockIdx.x * blockDim.x + threadIdx.x;
    if (i < n4) {
        float4 f = ((const float4*)in)[i];
        ushort4 o;
        o.x = f2bf(f.x); o.y = f2bf(f.y); o.z = f2bf(f.z); o.w = f2bf(f.w);
        ((ushort4*)out)[i] = o;
    }
}

// ------------- single-buffer BK=64 core (R17): high-depth kernels ---------
// LDS: As/Bs each [128][64] ushort (16 KB each, 32 KB -> capacity 5/CU).
__device__ __forceinline__ void gemm128_core_sb64(
    const ushort* __restrict__ A, const ushort* __restrict__ B,
    int lda, int ldb, int m0, int n0, int kIters,
    ushort* As, ushort* Bs, f32x4 acc[4][4])
{
    const int tid  = threadIdx.x;
    const int lane = tid & 63, wave = tid >> 6;
    const int wm = (wave >> 1) * 64, wn = (wave & 1) * 64;
    const int quad = lane >> 4, l16 = lane & 15;
    const int srow8 = lane >> 3;
    const int gchk  = (lane & 7) ^ srow8;      // pre-swizzled global chunk
    const ushort* ag = A + (size_t)(m0 + wave * 32 + srow8) * lda + gchk * 8;
    const ushort* bg = B + (size_t)(n0 + wave * 32 + srow8) * ldb + gchk * 8;
    const int p0 = quad ^ (l16 & 7);           // kk=0 read chunk; kk=1 is p0^4

    for (int kt = 0; kt < kIters; ++kt) {
        const int k0 = kt * 64;
#pragma unroll
        for (int s = 0; s < 4; ++s) {
            async_load16(ag + k0 + (size_t)(s * 8) * lda,
                         As + (wave * 32 + s * 8) * 64);
            async_load16(bg + k0 + (size_t)(s * 8) * ldb,
                         Bs + (wave * 32 + s * 8) * 64);
        }
        __syncthreads();
#pragma unroll
        for (int kk = 0; kk < 2; ++kk) {
            const int poff = (p0 ^ (kk << 2)) * 8;
            bf16x8 aF[4], bF[4];
#pragma unroll
            for (int i = 0; i < 4; ++i)
                aF[i] = *(const bf16x8*)(As + (wm + i * 16 + l16) * 64 + poff);
#pragma unroll
            for (int j = 0; j < 4; ++j)
                bF[j] = *(const bf16x8*)(Bs + (wn + j * 16 + l16) * 64 + poff);
#pragma unroll
            for (int i = 0; i < 4; ++i)
#pragma unroll
                for (int j = 0; j < 4; ++j)
                    acc[i][j] = __builtin_amdgcn_mfma_f32_16x16x32_bf16(aF[i], bF[j], acc[i][j], 0, 0, 0);
        }
        __syncthreads();
    }
}

// ------------- double-buffered BK=64 core (R17): scores/pv ----------------
// LDS: As/Bs each [2][128][64] ushort (32 KB each, 64 KB total).
__device__ __forceinline__ void gemm128_core_db64(
    const ushort* __restrict__ A, const ushort* __restrict__ B,
    int lda, int ldb, int m0, int n0, int kIters,
    ushort* As, ushort* Bs, f32x4 acc[4][4])
{
    const int tid  = threadIdx.x;
    const int lane = tid & 63, wave = tid >> 6;
    const int wm = (wave >> 1) * 64, wn = (wave & 1) * 64;
    const int quad = lane >> 4, l16 = lane & 15;
    const int srow8 = lane >> 3;
    const int gchk  = (lane & 7) ^ srow8;
    const ushort* ag = A + (size_t)(m0 + wave * 32 + srow8) * lda + gchk * 8;
    const ushort* bg = B + (size_t)(n0 + wave * 32 + srow8) * ldb + gchk * 8;
    const int p0 = quad ^ (l16 & 7);

#define STAGE64(K0, NB) do {                                            \
        _Pragma("unroll")                                               \
        for (int s = 0; s < 4; ++s) {                                   \
            async_load16(ag + (K0) + (size_t)(s * 8) * lda,             \
                         As + (NB) + (wave * 32 + s * 8) * 64);         \
            async_load16(bg + (K0) + (size_t)(s * 8) * ldb,             \
                         Bs + (NB) + (wave * 32 + s * 8) * 64);         \
        }                                                               \
    } while (0)

    STAGE64(0, 0);
    __syncthreads();

    int cur = 0;
    for (int kt = 0; kt < kIters; ++kt) {
        if (kt + 1 < kIters) STAGE64((kt + 1) * 64, (cur ^ 1) * 8192);
        const ushort* as = As + cur * 8192;
        const ushort* bs = Bs + cur * 8192;
#pragma unroll
        for (int kk = 0; kk < 2; ++kk) {
            const int poff = (p0 ^ (kk << 2)) * 8;
            bf16x8 aF[4], bF[4];
#pragma unroll
            for (int i = 0; i < 4; ++i)
                aF[i] = *(const bf16x8*)(as + (wm + i * 16 + l16) * 64 + poff);
#pragma unroll
            for (int j = 0; j < 4; ++j)
                bF[j] = *(const bf16x8*)(bs + (wn + j * 16 + l16) * 64 + poff);
#pragma unroll
            for (int i = 0; i < 4; ++i)
#pragma unroll
                for (int j = 0; j < 4; ++j)
                    acc[i][j] = __builtin_amdgcn_mfma_f32_16x16x32_bf16(aF[i], bF[j], acc[i][j], 0, 0, 0);
        }
        __syncthreads();
        cur ^= 1;
    }
#undef STAGE64
}

#define ACC_INIT4(acc) \
    _Pragma("unroll") for (int i = 0; i < 4; ++i) \
    _Pragma("unroll") for (int j = 0; j < 4; ++j) \
    _Pragma("unroll") for (int r = 0; r < 4; ++r) acc[i][j][r] = 0.0f;

// QKV + RoPE. grid (1536): lid -> XCD-chunked swz -> (m-tile, n-tile, z).
// Consecutive lids share the weight B-panel -> chunk of 192 per XCD.
__global__ __launch_bounds__(256) void qkv_rope_kernel(
    const ushort* __restrict__ xb, const ushort* __restrict__ wq,
    const ushort* __restrict__ wk, const ushort* __restrict__ wv,
    const float2* __restrict__ cs,
    ushort* __restrict__ Qr, ushort* __restrict__ Kr, ushort* __restrict__ VT)
{
    __shared__ __attribute__((aligned(16))) ushort As[128 * 64];
    __shared__ __attribute__((aligned(16))) ushort Bs[128 * 64];
    const int lid = blockIdx.x;
    const int swz = (lid & 7) * 192 + (lid >> 3);   // bijective: 1536 = 8*192
    const int m0 = (swz & 63) * 128;
    const int tq = swz >> 6;                        // 0..23
    const int n0 = (tq & 7) * 128;
    const int z  = tq >> 3;                         // 0..2
    const ushort* W = (z == 0) ? wq : (z == 1) ? wk : wv;

    f32x4 acc[4][4];
    ACC_INIT4(acc)
    gemm128_core_sb64(xb, W, 1024, 1024, m0, n0, 16, As, Bs, acc);

    const int lane = threadIdx.x & 63, wave = threadIdx.x >> 6;
    const int wm = (wave >> 1) * 64, wn = (wave & 1) * 64;
    const int quad = lane >> 4, l16 = lane & 15;

    if (z < 2) {
        ushort* out = (z == 0) ? Qr : Kr;
#pragma unroll
        for (int j = 0; j < 4; ++j) {
            const int n = n0 + wn + j * 16 + l16;
            const int iidx = n >> 1;
            const bool odd = n & 1;
#pragma unroll
            for (int i = 0; i < 4; ++i) {
                const int mbase = m0 + wm + i * 16 + quad * 4;
                const int pos0  = mbase & 2047;
                const float2* csp = cs + (size_t)pos0 * 512 + iidx;
#pragma unroll
                for (int r = 0; r < 4; ++r) {
                    const float2 sc = csp[(size_t)r * 512]; // (cos, sin) at pos0+r
                    float v = acc[i][j][r];
                    float p = __shfl_xor(v, 1);   // partner column n^1, same row
                    float o = odd ? (v * sc.x - p * sc.y) : (v * sc.x + p * sc.y);
                    out[(size_t)(mbase + r) * 1024 + n] = f2bf(o);
                }
            }
        }
    } else {
        // V transposed: VT[b][n][pos]; 4 consecutive pos per quad -> ushort4
#pragma unroll
        for (int i = 0; i < 4; ++i) {
            const int mbase = m0 + wm + i * 16 + quad * 4;
            const int b = mbase >> 11, pos0 = mbase & 2047;
#pragma unroll
            for (int j = 0; j < 4; ++j) {
                const int n = n0 + wn + j * 16 + l16;
                ushort4 o;
                o.x = f2bf(acc[i][j][0]); o.y = f2bf(acc[i][j][1]);
                o.z = f2bf(acc[i][j][2]); o.w = f2bf(acc[i][j][3]);
                *(ushort4*)(VT + ((size_t)b * 1024 + n) * 2048 + pos0) = o;
            }
        }
    }
}

// scores: grid (544) = 4 batches x 136 active lower-triangle tiles.
// XCD-chunked swz (68/XCD); row-major triangular decode (consecutive t
// share the Q-panel; small-nt K-panels recur within a chunk). db64 core.
__global__ __launch_bounds__(256) void scores_kernel(
    const ushort* __restrict__ Qr, const ushort* __restrict__ Kr,
    float* __restrict__ S)
{
    const int lid = blockIdx.x;
    const int swz = (lid & 7) * 68 + (lid >> 3);    // bijective: 544 = 8*68
    const int b = swz / 136;
    const int t = swz - b * 136;
    int mt = (int)((sqrtf(8.0f * (float)t + 1.0f) - 1.0f) * 0.5f);
    while ((mt + 1) * (mt + 2) / 2 <= t) ++mt;      // fixup float edge cases
    while (mt * (mt + 1) / 2 > t) --mt;
    const int nt = t - mt * (mt + 1) / 2;
    const int m0 = mt * 128;
    const int n0 = nt * 128;

    __shared__ __attribute__((aligned(16))) ushort As[2 * 128 * 64];
    __shared__ __attribute__((aligned(16))) ushort Bs[2 * 128 * 64];
    const ushort* A = Qr + (size_t)b * 2048 * 1024;
    const ushort* B = Kr + (size_t)b * 2048 * 1024;
    float* Sb = S + (size_t)b * 2048 * 2048;

    f32x4 acc[4][4];
    ACC_INIT4(acc)
    gemm128_core_db64(A, B, 1024, 1024, m0, n0, 16, As, Bs, acc);

    const int lane = threadIdx.x & 63, wave = threadIdx.x >> 6;
    const int wm = (wave >> 1) * 64, wn = (wave & 1) * 64;
    const int quad = lane >> 4, l16 = lane & 15;
#pragma unroll
    for (int i = 0; i < 4; ++i)
#pragma unroll
        for (int j = 0; j < 4; ++j) {
            const int n = n0 + wn + j * 16 + l16;
#pragma unroll
            for (int r = 0; r < 4; ++r) {
                const int m = m0 + wm + i * 16 + quad * 4 + r;
                Sb[(size_t)m * 2048 + n] = acc[i][j][r] * 0.03125f;
            }
        }
}

// Row softmax, register-staged, wave-parallel reduction (3 barriers).
// Reads clipped to nvalid; writes clipped to roundup(row+1,128).
__global__ __launch_bounds__(256) void softmax_kernel(
    const float* __restrict__ S, ushort* __restrict__ P)
{
    __shared__ float red[4];
    const int row = blockIdx.x, tid = threadIdx.x, b = blockIdx.y;
    const int lane = tid & 63, wave = tid >> 6;
    const float* s = S + ((size_t)b * 2048 + row) * 2048;
    ushort*      p = P + ((size_t)b * 2048 + row) * 2048;
    const int nvalid = row + 1;
    const int wlimit = (row & ~127) + 128;
    const int j0 = tid * 8;

    float v[8] = {0.0f, 0.0f, 0.0f, 0.0f, 0.0f, 0.0f, 0.0f, 0.0f};
    if (j0 < nvalid) {
        float4 f0 = *(const float4*)(s + j0);
        v[0]=f0.x; v[1]=f0.y; v[2]=f0.z; v[3]=f0.w;
    }
    if (j0 + 4 < nvalid) {
        float4 f1 = *(const float4*)(s + j0 + 4);
        v[4]=f1.x; v[5]=f1.y; v[6]=f1.z; v[7]=f1.w;
    }

    float mx = -3.402823466e38f;
#pragma unroll
    for (int u = 0; u < 8; ++u) if (j0 + u < nvalid) mx = fmaxf(mx, v[u]);
#pragma unroll
    for (int d = 1; d < 64; d <<= 1) mx = fmaxf(mx, __shfl_xor(mx, d));
    if (lane == 0) red[wave] = mx;
    __syncthreads();
    mx = fmaxf(fmaxf(red[0], red[1]), fmaxf(red[2], red[3]));

    float sum = 0.0f;
#pragma unroll
    for (int u = 0; u < 8; ++u) {
        v[u] = (j0 + u < nvalid) ? __expf(v[u] - mx) : 0.0f;
        sum += v[u];
    }
#pragma unroll
    for (int d = 1; d < 64; d <<= 1) sum += __shfl_xor(sum, d);
    __syncthreads();                 // all reads of red done before overwrite
    if (lane == 0) red[wave] = sum;
    __syncthreads();
    const float inv = 1.0f / (red[0] + red[1] + red[2] + red[3]);

    if (j0 < wlimit) {
        ushort o[8];
#pragma unroll
        for (int u = 0; u < 8; ++u) o[u] = f2bf(v[u] * inv);
        *(int4*)(p + j0) = *(const int4*)o;
    }
}

// pv: grid (512): lid -> XCD-chunked swz -> (x,y,b); consecutive lids share
// the V-panel (all 16 m-tiles of one (n,b)) -> 4 complete panels per XCD.
// m-interleave kept for K-balance. db64 core, causal k-limit.
__global__ __launch_bounds__(256) void pv_kernel(
    const ushort* __restrict__ P, const ushort* __restrict__ VT,
    float* __restrict__ out)
{
    __shared__ __attribute__((aligned(16))) ushort As[2 * 128 * 64];
    __shared__ __attribute__((aligned(16))) ushort Bs[2 * 128 * 64];
    const int lid = blockIdx.x;
    const int swz = (lid & 7) * 64 + (lid >> 3);    // bijective: 512 = 8*64
    const int x  = swz & 15;
    const int yy = (swz >> 4) & 7;
    const int b  = swz >> 7;
    const int mt = (x & 1) ? (15 - (x >> 1)) : (x >> 1);  // 0,15,1,14,...
    const int m0 = mt * 128;
    const int n0 = yy * 128;
    const ushort* A = P + (size_t)b * 2048 * 2048;
    const ushort* B = VT + (size_t)b * 1024 * 2048;
    const int kIters = (m0 + 128) / 64;   // causal: P[m][k]=0 for k>m

    f32x4 acc[4][4];
    ACC_INIT4(acc)
    gemm128_core_db64(A, B, 2048, 2048, m0, n0, kIters, As, Bs, acc);

    const int lane = threadIdx.x & 63, wave = threadIdx.x >> 6;
    const int wm = (wave >> 1) * 64, wn = (wave & 1) * 64;
    const int quad = lane >> 4, l16 = lane & 15;
#pragma unroll
    for (int i = 0; i < 4; ++i)
#pragma unroll
        for (int j = 0; j < 4; ++j) {
            const int n = n0 + wn + j * 16 + l16;
#pragma unroll
            for (int r = 0; r < 4; ++r) {
                const int m = m0 + wm + i * 16 + quad * 4 + r;
                out[((size_t)b * 2048 + m) * 1024 + n] = acc[i][j][r];
            }
        }
}

extern "C" void kernel_launch(void* const* d_in, const int* in_sizes, int n_in,
                              void* d_out, int out_size, void* d_ws, size_t ws_size,
                              hipStream_t stream) {
    const float* x  = (const float*)d_in[0];
    const float* wq = (const float*)d_in[1];
    const float* wk = (const float*)d_in[2];
    const float* wv = (const float*)d_in[3];

    const size_t MiB = 1024 * 1024;
    char* ws = (char*)d_ws;
    ushort* xb  = (ushort*)(ws);              //  16 MiB [8192][1024] bf16
    ushort* wqb = (ushort*)(ws +  16 * MiB);  //   2 MiB
    ushort* wkb = (ushort*)(ws +  18 * MiB);  //   2 MiB
    ushort* wvb = (ushort*)(ws +  20 * MiB);  //   2 MiB
    ushort* Qr  = (ushort*)(ws +  22 * MiB);  //  16 MiB [4][2048][1024] bf16
    ushort* Kr  = (ushort*)(ws +  38 * MiB);  //  16 MiB
    ushort* VT  = (ushort*)(ws +  54 * MiB);  //  16 MiB [4][1024][2048] bf16
    float*  S   = (float* )(ws +  70 * MiB);  //  64 MiB [4][2048][2048] f32
    ushort* P   = (ushort*)(ws + 134 * MiB);  //  32 MiB [4][2048][2048] bf16
    float2* cs  = (float2*)(ws + 166 * MiB);  //   8 MiB [2048][512] (cos,sin) f32
    float*  out = (float*)d_out;              // ws use: 174 MiB (256 avail)

    cvt_all_kernel <<<dim3(8192, 5),   256, 0, stream>>>(x, wq, wk, wv, xb, wqb, wkb, wvb, cs);
    qkv_rope_kernel<<<dim3(1536),      256, 0, stream>>>(xb, wqb, wkb, wvb, cs, Qr, Kr, VT);
    scores_kernel  <<<dim3(544),       256, 0, stream>>>(Qr, Kr, S);
    softmax_kernel <<<dim3(2048, 4),   256, 0, stream>>>(S, P);
    pv_kernel      <<<dim3(512),       256, 0, stream>>>(P, VT, out);
}

// Round 12
// 258.499 us; speedup vs baseline: 1.0549x; 1.0549x over previous
//
#include <hip/hip_runtime.h>
#include <hip/hip_bf16.h>
#include <math.h>

// R22: RESTORE R17 byte-identical (session best, 257.4us measured @ R7).
// R21 post-mortem: XCD-chunked swizzle (T1) null-to-negative - qkv L2-miss
// traffic 57->208MB (chunk co-residency spans all 64 m-tiles on one XCD,
// thrashing its 4MB L2); natural dispatch order already optimal (consecutive
// lids share W-panel + adjacent m, round-robin keeps each XCD's resident
// window tight). T1's prereq (HBM-bound panel re-fetch) absent here.
// Ledger: scores/pv ~250 GF/s invariant under {db32,db64,sb64,ring,
// depth 2->4.25, XCD swizzle} (R13/R14/R18/R20/R21). qkv sb64 83-88us
// stable. Remaining untested lever = full 8-phase fine interleave (m218);
// one-shot-risk rewrite, not taken this round.
// Config: cvt+cos/sin table; qkv sb64 BK=64 grid(64,8,3); scores db64
// full-K grid(16,16,4) early-return; softmax single-S wave-parallel with
// read/write clip; pv db64 + m-interleave, causal k-limit.
// LDS swizzle (verified, conflicts=0): row holds 8 chunks, phys p at row r
// = logical p^(r&7); staging pre-swizzles GLOBAL chunk ((l&7)^(l>>3)), LDS
// dest linear (m104/m173); read phys = (quad^(kk<<2))^(l16&7).

typedef __bf16 bf16x8 __attribute__((ext_vector_type(8)));
typedef float  f32x4  __attribute__((ext_vector_type(4)));

__device__ __forceinline__ ushort f2bf(float f) {
    __hip_bfloat16 h = __float2bfloat16(f);
    return *reinterpret_cast<ushort*>(&h);
}

__device__ __forceinline__ void async_load16(const ushort* g, ushort* l) {
    __builtin_amdgcn_global_load_lds(
        (const __attribute__((address_space(1))) void*)g,
        (__attribute__((address_space(3))) void*)l, 16, 0, 0);
}

// One launch for all 4 fp32->bf16 conversions + RoPE cos/sin table.
// grid (8192, 5): y<4 = conversions, y==4 = table gen (first 4096 x-blocks).
__global__ __launch_bounds__(256) void cvt_all_kernel(
    const float* __restrict__ x,  const float* __restrict__ wq,
    const float* __restrict__ wk, const float* __restrict__ wv,
    ushort* __restrict__ xb, ushort* __restrict__ wqb,
    ushort* __restrict__ wkb, ushort* __restrict__ wvb,
    float2* __restrict__ cs)
{
    const int t = blockIdx.y;
    if (t == 4) {
        // cs[pos*512 + i] = (cos(pos*phi_i), sin(pos*phi_i)),
        // phi_i = 10000^(-2*(i-1)/1024)  (reference's -1 quirk preserved).
        const int idx = blockIdx.x * 256 + threadIdx.x;
        if (idx < 2048 * 512) {
            const int pos = idx >> 9, i = idx & 511;
            const float phi = powf(10000.0f, -2.0f * ((float)i - 1.0f) / 1024.0f);
            float s, c;
            sincosf((float)pos * phi, &s, &c);
            cs[idx] = make_float2(c, s);
        }
        return;
    }
    const float* in  = (t == 0) ? x  : (t == 1) ? wq  : (t == 2) ? wk  : wv;
    ushort*      out = (t == 0) ? xb : (t == 1) ? wqb : (t == 2) ? wkb : wvb;
    const int n4 = (t == 0) ? 2097152 : 262144;
    int i = blockIdx.x * blockDim.x + threadIdx.x;
    if (i < n4) {
        float4 f = ((const float4*)in)[i];
        ushort4 o;
        o.x = f2bf(f.x); o.y = f2bf(f.y); o.z = f2bf(f.z); o.w = f2bf(f.w);
        ((ushort4*)out)[i] = o;
    }
}

// ------------- single-buffer BK=64 core: high-depth kernels ---------------
// LDS: As/Bs each [128][64] ushort (16 KB each, 32 KB -> capacity 5/CU).
__device__ __forceinline__ void gemm128_core_sb64(
    const ushort* __restrict__ A, const ushort* __restrict__ B,
    int lda, int ldb, int m0, int n0, int kIters,
    ushort* As, ushort* Bs, f32x4 acc[4][4])
{
    const int tid  = threadIdx.x;
    const int lane = tid & 63, wave = tid >> 6;
    const int wm = (wave >> 1) * 64, wn = (wave & 1) * 64;
    const int quad = lane >> 4, l16 = lane & 15;
    const int srow8 = lane >> 3;
    const int gchk  = (lane & 7) ^ srow8;      // pre-swizzled global chunk
    const ushort* ag = A + (size_t)(m0 + wave * 32 + srow8) * lda + gchk * 8;
    const ushort* bg = B + (size_t)(n0 + wave * 32 + srow8) * ldb + gchk * 8;
    const int p0 = quad ^ (l16 & 7);           // kk=0 read chunk; kk=1 is p0^4

    for (int kt = 0; kt < kIters; ++kt) {
        const int k0 = kt * 64;
#pragma unroll
        for (int s = 0; s < 4; ++s) {
            async_load16(ag + k0 + (size_t)(s * 8) * lda,
                         As + (wave * 32 + s * 8) * 64);
            async_load16(bg + k0 + (size_t)(s * 8) * ldb,
                         Bs + (wave * 32 + s * 8) * 64);
        }
        __syncthreads();
#pragma unroll
        for (int kk = 0; kk < 2; ++kk) {
            const int poff = (p0 ^ (kk << 2)) * 8;
            bf16x8 aF[4], bF[4];
#pragma unroll
            for (int i = 0; i < 4; ++i)
                aF[i] = *(const bf16x8*)(As + (wm + i * 16 + l16) * 64 + poff);
#pragma unroll
            for (int j = 0; j < 4; ++j)
                bF[j] = *(const bf16x8*)(Bs + (wn + j * 16 + l16) * 64 + poff);
#pragma unroll
            for (int i = 0; i < 4; ++i)
#pragma unroll
                for (int j = 0; j < 4; ++j)
                    acc[i][j] = __builtin_amdgcn_mfma_f32_16x16x32_bf16(aF[i], bF[j], acc[i][j], 0, 0, 0);
        }
        __syncthreads();
    }
}

// ------------- double-buffered BK=64 core: scores/pv ----------------------
// LDS: As/Bs each [2][128][64] ushort (32 KB each, 64 KB total).
__device__ __forceinline__ void gemm128_core_db64(
    const ushort* __restrict__ A, const ushort* __restrict__ B,
    int lda, int ldb, int m0, int n0, int kIters,
    ushort* As, ushort* Bs, f32x4 acc[4][4])
{
    const int tid  = threadIdx.x;
    const int lane = tid & 63, wave = tid >> 6;
    const int wm = (wave >> 1) * 64, wn = (wave & 1) * 64;
    const int quad = lane >> 4, l16 = lane & 15;
    const int srow8 = lane >> 3;
    const int gchk  = (lane & 7) ^ srow8;
    const ushort* ag = A + (size_t)(m0 + wave * 32 + srow8) * lda + gchk * 8;
    const ushort* bg = B + (size_t)(n0 + wave * 32 + srow8) * ldb + gchk * 8;
    const int p0 = quad ^ (l16 & 7);

#define STAGE64(K0, NB) do {                                            \
        _Pragma("unroll")                                               \
        for (int s = 0; s < 4; ++s) {                                   \
            async_load16(ag + (K0) + (size_t)(s * 8) * lda,             \
                         As + (NB) + (wave * 32 + s * 8) * 64);         \
            async_load16(bg + (K0) + (size_t)(s * 8) * ldb,             \
                         Bs + (NB) + (wave * 32 + s * 8) * 64);         \
        }                                                               \
    } while (0)

    STAGE64(0, 0);
    __syncthreads();

    int cur = 0;
    for (int kt = 0; kt < kIters; ++kt) {
        if (kt + 1 < kIters) STAGE64((kt + 1) * 64, (cur ^ 1) * 8192);
        const ushort* as = As + cur * 8192;
        const ushort* bs = Bs + cur * 8192;
#pragma unroll
        for (int kk = 0; kk < 2; ++kk) {
            const int poff = (p0 ^ (kk << 2)) * 8;
            bf16x8 aF[4], bF[4];
#pragma unroll
            for (int i = 0; i < 4; ++i)
                aF[i] = *(const bf16x8*)(as + (wm + i * 16 + l16) * 64 + poff);
#pragma unroll
            for (int j = 0; j < 4; ++j)
                bF[j] = *(const bf16x8*)(bs + (wn + j * 16 + l16) * 64 + poff);
#pragma unroll
            for (int i = 0; i < 4; ++i)
#pragma unroll
                for (int j = 0; j < 4; ++j)
                    acc[i][j] = __builtin_amdgcn_mfma_f32_16x16x32_bf16(aF[i], bF[j], acc[i][j], 0, 0, 0);
        }
        __syncthreads();
        cur ^= 1;
    }
#undef STAGE64
}

#define ACC_INIT4(acc) \
    _Pragma("unroll") for (int i = 0; i < 4; ++i) \
    _Pragma("unroll") for (int j = 0; j < 4; ++j) \
    _Pragma("unroll") for (int r = 0; r < 4; ++r) acc[i][j][r] = 0.0f;

// QKV + RoPE, z-split. grid (64, 8, 3). sb64 core.
__global__ __launch_bounds__(256) void qkv_rope_kernel(
    const ushort* __restrict__ xb, const ushort* __restrict__ wq,
    const ushort* __restrict__ wk, const ushort* __restrict__ wv,
    const float2* __restrict__ cs,
    ushort* __restrict__ Qr, ushort* __restrict__ Kr, ushort* __restrict__ VT)
{
    __shared__ __attribute__((aligned(16))) ushort As[128 * 64];
    __shared__ __attribute__((aligned(16))) ushort Bs[128 * 64];
    const int m0 = blockIdx.x * 128;
    const int n0 = blockIdx.y * 128;
    const int z  = blockIdx.z;
    const ushort* W = (z == 0) ? wq : (z == 1) ? wk : wv;

    f32x4 acc[4][4];
    ACC_INIT4(acc)
    gemm128_core_sb64(xb, W, 1024, 1024, m0, n0, 16, As, Bs, acc);

    const int lane = threadIdx.x & 63, wave = threadIdx.x >> 6;
    const int wm = (wave >> 1) * 64, wn = (wave & 1) * 64;
    const int quad = lane >> 4, l16 = lane & 15;

    if (z < 2) {
        ushort* out = (z == 0) ? Qr : Kr;
#pragma unroll
        for (int j = 0; j < 4; ++j) {
            const int n = n0 + wn + j * 16 + l16;
            const int iidx = n >> 1;
            const bool odd = n & 1;
#pragma unroll
            for (int i = 0; i < 4; ++i) {
                const int mbase = m0 + wm + i * 16 + quad * 4;
                const int pos0  = mbase & 2047;
                const float2* csp = cs + (size_t)pos0 * 512 + iidx;
#pragma unroll
                for (int r = 0; r < 4; ++r) {
                    const float2 sc = csp[(size_t)r * 512]; // (cos, sin) at pos0+r
                    float v = acc[i][j][r];
                    float p = __shfl_xor(v, 1);   // partner column n^1, same row
                    float o = odd ? (v * sc.x - p * sc.y) : (v * sc.x + p * sc.y);
                    out[(size_t)(mbase + r) * 1024 + n] = f2bf(o);
                }
            }
        }
    } else {
        // V transposed: VT[b][n][pos]; 4 consecutive pos per quad -> ushort4
#pragma unroll
        for (int i = 0; i < 4; ++i) {
            const int mbase = m0 + wm + i * 16 + quad * 4;
            const int b = mbase >> 11, pos0 = mbase & 2047;
#pragma unroll
            for (int j = 0; j < 4; ++j) {
                const int n = n0 + wn + j * 16 + l16;
                ushort4 o;
                o.x = f2bf(acc[i][j][0]); o.y = f2bf(acc[i][j][1]);
                o.z = f2bf(acc[i][j][2]); o.w = f2bf(acc[i][j][3]);
                *(ushort4*)(VT + ((size_t)b * 1024 + n) * 2048 + pos0) = o;
            }
        }
    }
}

// scores: grid (16, 16, 4); lower tiles only; S fp32 scaled 1/32. db64 core.
__global__ __launch_bounds__(256) void scores_kernel(
    const ushort* __restrict__ Qr, const ushort* __restrict__ Kr,
    float* __restrict__ S)
{
    const int m0 = blockIdx.x * 128;
    const int n0 = blockIdx.y * 128;
    if (n0 > m0 + 127) return;
    const int b = blockIdx.z;
    __shared__ __attribute__((aligned(16))) ushort As[2 * 128 * 64];
    __shared__ __attribute__((aligned(16))) ushort Bs[2 * 128 * 64];
    const ushort* A = Qr + (size_t)b * 2048 * 1024;
    const ushort* B = Kr + (size_t)b * 2048 * 1024;
    float* Sb = S + (size_t)b * 2048 * 2048;

    f32x4 acc[4][4];
    ACC_INIT4(acc)
    gemm128_core_db64(A, B, 1024, 1024, m0, n0, 16, As, Bs, acc);

    const int lane = threadIdx.x & 63, wave = threadIdx.x >> 6;
    const int wm = (wave >> 1) * 64, wn = (wave & 1) * 64;
    const int quad = lane >> 4, l16 = lane & 15;
#pragma unroll
    for (int i = 0; i < 4; ++i)
#pragma unroll
        for (int j = 0; j < 4; ++j) {
            const int n = n0 + wn + j * 16 + l16;
#pragma unroll
            for (int r = 0; r < 4; ++r) {
                const int m = m0 + wm + i * 16 + quad * 4 + r;
                Sb[(size_t)m * 2048 + n] = acc[i][j][r] * 0.03125f;
            }
        }
}

// Row softmax, register-staged, wave-parallel reduction (3 barriers).
// Reads clipped to nvalid; writes clipped to roundup(row+1,128).
__global__ __launch_bounds__(256) void softmax_kernel(
    const float* __restrict__ S, ushort* __restrict__ P)
{
    __shared__ float red[4];
    const int row = blockIdx.x, tid = threadIdx.x, b = blockIdx.y;
    const int lane = tid & 63, wave = tid >> 6;
    const float* s = S + ((size_t)b * 2048 + row) * 2048;
    ushort*      p = P + ((size_t)b * 2048 + row) * 2048;
    const int nvalid = row + 1;
    const int wlimit = (row & ~127) + 128;
    const int j0 = tid * 8;

    float v[8] = {0.0f, 0.0f, 0.0f, 0.0f, 0.0f, 0.0f, 0.0f, 0.0f};
    if (j0 < nvalid) {
        float4 f0 = *(const float4*)(s + j0);
        v[0]=f0.x; v[1]=f0.y; v[2]=f0.z; v[3]=f0.w;
    }
    if (j0 + 4 < nvalid) {
        float4 f1 = *(const float4*)(s + j0 + 4);
        v[4]=f1.x; v[5]=f1.y; v[6]=f1.z; v[7]=f1.w;
    }

    float mx = -3.402823466e38f;
#pragma unroll
    for (int u = 0; u < 8; ++u) if (j0 + u < nvalid) mx = fmaxf(mx, v[u]);
#pragma unroll
    for (int d = 1; d < 64; d <<= 1) mx = fmaxf(mx, __shfl_xor(mx, d));
    if (lane == 0) red[wave] = mx;
    __syncthreads();
    mx = fmaxf(fmaxf(red[0], red[1]), fmaxf(red[2], red[3]));

    float sum = 0.0f;
#pragma unroll
    for (int u = 0; u < 8; ++u) {
        v[u] = (j0 + u < nvalid) ? __expf(v[u] - mx) : 0.0f;
        sum += v[u];
    }
#pragma unroll
    for (int d = 1; d < 64; d <<= 1) sum += __shfl_xor(sum, d);
    __syncthreads();                 // all reads of red done before overwrite
    if (lane == 0) red[wave] = sum;
    __syncthreads();
    const float inv = 1.0f / (red[0] + red[1] + red[2] + red[3]);

    if (j0 < wlimit) {
        ushort o[8];
#pragma unroll
        for (int u = 0; u < 8; ++u) o[u] = f2bf(v[u] * inv);
        *(int4*)(p + j0) = *(const int4*)o;
    }
}

// pv: grid (16, 8, 4); causal k-limit; db64 core; m-tile interleave.
__global__ __launch_bounds__(256) void pv_kernel(
    const ushort* __restrict__ P, const ushort* __restrict__ VT,
    float* __restrict__ out)
{
    __shared__ __attribute__((aligned(16))) ushort As[2 * 128 * 64];
    __shared__ __attribute__((aligned(16))) ushort Bs[2 * 128 * 64];
    const int x  = blockIdx.x;
    const int mt = (x & 1) ? (15 - (x >> 1)) : (x >> 1);  // 0,15,1,14,...
    const int m0 = mt * 128;
    const int n0 = blockIdx.y * 128;
    const int b  = blockIdx.z;
    const ushort* A = P + (size_t)b * 2048 * 2048;
    const ushort* B = VT + (size_t)b * 1024 * 2048;
    const int kIters = (m0 + 128) / 64;   // causal: P[m][k]=0 for k>m

    f32x4 acc[4][4];
    ACC_INIT4(acc)
    gemm128_core_db64(A, B, 2048, 2048, m0, n0, kIters, As, Bs, acc);

    const int lane = threadIdx.x & 63, wave = threadIdx.x >> 6;
    const int wm = (wave >> 1) * 64, wn = (wave & 1) * 64;
    const int quad = lane >> 4, l16 = lane & 15;
#pragma unroll
    for (int i = 0; i < 4; ++i)
#pragma unroll
        for (int j = 0; j < 4; ++j) {
            const int n = n0 + wn + j * 16 + l16;
#pragma unroll
            for (int r = 0; r < 4; ++r) {
                const int m = m0 + wm + i * 16 + quad * 4 + r;
                out[((size_t)b * 2048 + m) * 1024 + n] = acc[i][j][r];
            }
        }
}

extern "C" void kernel_launch(void* const* d_in, const int* in_sizes, int n_in,
                              void* d_out, int out_size, void* d_ws, size_t ws_size,
                              hipStream_t stream) {
    const float* x  = (const float*)d_in[0];
    const float* wq = (const float*)d_in[1];
    const float* wk = (const float*)d_in[2];
    const float* wv = (const float*)d_in[3];

    const size_t MiB = 1024 * 1024;
    char* ws = (char*)d_ws;
    ushort* xb  = (ushort*)(ws);              //  16 MiB [8192][1024] bf16
    ushort* wqb = (ushort*)(ws +  16 * MiB);  //   2 MiB
    ushort* wkb = (ushort*)(ws +  18 * MiB);  //   2 MiB
    ushort* wvb = (ushort*)(ws +  20 * MiB);  //   2 MiB
    ushort* Qr  = (ushort*)(ws +  22 * MiB);  //  16 MiB [4][2048][1024] bf16
    ushort* Kr  = (ushort*)(ws +  38 * MiB);  //  16 MiB
    ushort* VT  = (ushort*)(ws +  54 * MiB);  //  16 MiB [4][1024][2048] bf16
    float*  S   = (float* )(ws +  70 * MiB);  //  64 MiB [4][2048][2048] f32
    ushort* P   = (ushort*)(ws + 134 * MiB);  //  32 MiB [4][2048][2048] bf16
    float2* cs  = (float2*)(ws + 166 * MiB);  //   8 MiB [2048][512] (cos,sin) f32
    float*  out = (float*)d_out;              // ws use: 174 MiB (256 avail)

    cvt_all_kernel <<<dim3(8192, 5),   256, 0, stream>>>(x, wq, wk, wv, xb, wqb, wkb, wvb, cs);
    qkv_rope_kernel<<<dim3(64, 8, 3),  256, 0, stream>>>(xb, wqb, wkb, wvb, cs, Qr, Kr, VT);
    scores_kernel  <<<dim3(16, 16, 4), 256, 0, stream>>>(Qr, Kr, S);
    softmax_kernel <<<dim3(2048, 4),   256, 0, stream>>>(S, P);
    pv_kernel      <<<dim3(16, 8, 4),  256, 0, stream>>>(P, VT, out);
}